// Round 14
// baseline (200.404 us; speedup 1.0000x reference)
//
#include <hip/hip_runtime.h>
#include <hip/hip_cooperative_groups.h>

namespace cg = cooperative_groups;

#define E 128
#define OFF_Q 128
#define OFF_HEAD 256
#define OFF_REL 394
#define OFF_TAIL 522
#define KTOT 138      // 128 + 2 + 2*4
#define KP 160
#define AST 168       // LDS A row stride in bf16 for nodepre
#define RNGC 2048     // nodes per range bucket
#define NCHK 8        // chunks per range (scatter parallelism)
#define CAP 16384     // slots per bucket (expected ~12K, fixed input, big margin)

typedef __attribute__((ext_vector_type(8))) short short8;
typedef __attribute__((ext_vector_type(4))) float f32x4;

// ---- bf16 helpers (RNE, finite values only) ----
__device__ __forceinline__ unsigned short f2bf(float f) {
    unsigned u = __float_as_uint(f);
    return (unsigned short)((u + 0x7fffu + ((u >> 16) & 1u)) >> 16);
}
__device__ __forceinline__ unsigned bpack(float lo, float hi) {
    return (unsigned)f2bf(lo) | ((unsigned)f2bf(hi) << 16);
}
__device__ __forceinline__ float blo(unsigned u) { return __uint_as_float(u << 16); }
__device__ __forceinline__ float bhi(unsigned u) { return __uint_as_float(u & 0xffff0000u); }

// ---- cooperative scatter pipeline: zero-curs | bucket | scat1 | reduce1 | scat2 ----
// grid = RC*NCHK = 200 blocks x 1024 threads, phases separated by grid.sync()
__global__ __launch_bounds__(1024) void scatter_coop(
        const int* __restrict__ h_id, const int* __restrict__ t_id,
        const float* __restrict__ topic,
        unsigned* __restrict__ curs, unsigned* __restrict__ pairs_f,
        unsigned* __restrict__ pairs_r, float* __restrict__ part1,
        float* __restrict__ pef1, float* __restrict__ per1,
        float* __restrict__ inv_fwd, float* __restrict__ inv_rev,
        int T, int N) {
    cg::grid_group grid = cg::this_grid();
    __shared__ float bins[6][RNGC];
    __shared__ unsigned hf[32], hr[32], basef[32], baser[32];
    int tid = threadIdx.x;
    int bid = blockIdx.x;
    int gthreads = gridDim.x * 1024;

    // ---- P0: zero cursors ----
    if (bid == 0 && tid < 64) curs[tid] = 0;
    grid.sync();

    // ---- P1: bucket (counting-sort edges by dest range, both directions) ----
    for (int base = 0; base < T; base += gthreads * 4) {
        int e0 = base + (bid * 1024 + tid) * 4;
        int hh[4], tt[4];
        int cnt = 0;
        if (e0 < T) {
            if (e0 + 3 < T) {
                int4 h4 = *(const int4*)&h_id[e0];
                int4 t4 = *(const int4*)&t_id[e0];
                hh[0] = h4.x; hh[1] = h4.y; hh[2] = h4.z; hh[3] = h4.w;
                tt[0] = t4.x; tt[1] = t4.y; tt[2] = t4.z; tt[3] = t4.w;
                cnt = 4;
            } else {
                for (int j = 0; e0 + j < T && j < 4; ++j) {
                    hh[j] = h_id[e0 + j];
                    tt[j] = t_id[e0 + j];
                    ++cnt;
                }
            }
        }
        if (tid < 32) { hf[tid] = 0; hr[tid] = 0; }
        __syncthreads();
        unsigned bf[4], br[4];
        for (int j = 0; j < cnt; ++j) {
            bf[j] = (unsigned)tt[j] >> 11;
            br[j] = (unsigned)hh[j] >> 11;
            atomicAdd(&hf[bf[j]], 1u);
            atomicAdd(&hr[br[j]], 1u);
        }
        __syncthreads();
        if (tid < 32) {
            basef[tid] = hf[tid] ? atomicAdd(&curs[tid], hf[tid]) : 0u;
            baser[tid] = hr[tid] ? atomicAdd(&curs[32 + tid], hr[tid]) : 0u;
        }
        __syncthreads();
        if (tid < 32) { hf[tid] = 0; hr[tid] = 0; }
        __syncthreads();
        for (int j = 0; j < cnt; ++j) {
            unsigned sf = basef[bf[j]] + atomicAdd(&hf[bf[j]], 1u);
            if (sf < CAP) pairs_f[bf[j] * CAP + sf] =
                (unsigned)hh[j] | (((unsigned)tt[j] & 2047u) << 16);
            unsigned sr = baser[br[j]] + atomicAdd(&hr[br[j]], 1u);
            if (sr < CAP) pairs_r[br[j] * CAP + sr] =
                (unsigned)tt[j] | (((unsigned)hh[j] & 2047u) << 16);
        }
        __syncthreads();
    }
    grid.sync();

    // ---- P2: scat1 — range b, chunk ck; LDS bins; non-atomic partials ----
    {
        int b = bid / NCHK;
        int ck = bid % NCHK;
        for (int i = tid; i < 6 * RNGC; i += 1024) ((float*)bins)[i] = 0.f;
        __syncthreads();
        unsigned cf = min(curs[b], (unsigned)CAP);
        unsigned cr = min(curs[32 + b], (unsigned)CAP);
        const unsigned* pf = pairs_f + (size_t)b * CAP;
        const unsigned* pr = pairs_r + (size_t)b * CAP;
        unsigned lf = (cf + NCHK - 1) / NCHK;
        unsigned lr = (cr + NCHK - 1) / NCHK;
        unsigned f0 = ck * lf, f1e = min(cf, f0 + lf);
        unsigned r0 = ck * lr, r1e = min(cr, r0 + lr);
        for (unsigned i = f0 + tid; i < f1e; i += 1024) {
            unsigned p = pf[i];
            float2 v = *(const float2*)&topic[2 * (size_t)(p & 0xFFFFu)];
            int dl = p >> 16;
            atomicAdd(&bins[0][dl], v.x);
            atomicAdd(&bins[1][dl], v.y);
            atomicAdd(&bins[2][dl], 1.0f);
        }
        for (unsigned i = r0 + tid; i < r1e; i += 1024) {
            unsigned p = pr[i];
            float2 v = *(const float2*)&topic[2 * (size_t)(p & 0xFFFFu)];
            int dl = p >> 16;
            atomicAdd(&bins[3][dl], v.x);
            atomicAdd(&bins[4][dl], v.y);
            atomicAdd(&bins[5][dl], 1.0f);
        }
        __syncthreads();
        float* dst = part1 + ((size_t)(b * NCHK + ck) * 6) * RNGC;
#pragma unroll
        for (int c = 0; c < 6; ++c)
            for (int n = tid; n < RNGC; n += 1024)
                dst[c * RNGC + n] = bins[c][n];
    }
    grid.sync();

    // ---- P3: reduce1 -> scaled pef1/per1 + inv arrays ----
    for (int n = bid * 1024 + tid; n < N; n += gthreads) {
        int b = n >> 11, nl = n & 2047;
        float s[6] = {0.f, 0.f, 0.f, 0.f, 0.f, 0.f};
        const float* pbase = part1 + (size_t)b * NCHK * 6 * RNGC + nl;
#pragma unroll
        for (int ck = 0; ck < NCHK; ++ck)
#pragma unroll
            for (int c = 0; c < 6; ++c)
                s[c] += pbase[(ck * 6 + c) * RNGC];
        float invf = 1.0f / fmaxf(s[2], 1.0f);
        float invr = 1.0f / fmaxf(s[5], 1.0f);
        pef1[2 * n] = s[0] * invf;
        pef1[2 * n + 1] = s[1] * invf;
        per1[2 * n] = s[3] * invr;
        per1[2 * n + 1] = s[4] * invr;
        inv_fwd[n] = invf;
        inv_rev[n] = invr;
    }
    grid.sync();

    // ---- P4: scat2 — gathers scaled pef1/per1; partials overwrite part1 ----
    {
        int b = bid / NCHK;
        int ck = bid % NCHK;
        for (int i = tid; i < 4 * RNGC; i += 1024) ((float*)bins)[i] = 0.f;
        __syncthreads();
        unsigned cf = min(curs[b], (unsigned)CAP);
        unsigned cr = min(curs[32 + b], (unsigned)CAP);
        const unsigned* pf = pairs_f + (size_t)b * CAP;
        const unsigned* pr = pairs_r + (size_t)b * CAP;
        unsigned lf = (cf + NCHK - 1) / NCHK;
        unsigned lr = (cr + NCHK - 1) / NCHK;
        unsigned f0 = ck * lf, f1e = min(cf, f0 + lf);
        unsigned r0 = ck * lr, r1e = min(cr, r0 + lr);
        for (unsigned i = f0 + tid; i < f1e; i += 1024) {
            unsigned p = pf[i];
            float2 v = *(const float2*)&pef1[2 * (size_t)(p & 0xFFFFu)];
            int dl = p >> 16;
            atomicAdd(&bins[0][dl], v.x);
            atomicAdd(&bins[1][dl], v.y);
        }
        for (unsigned i = r0 + tid; i < r1e; i += 1024) {
            unsigned p = pr[i];
            float2 v = *(const float2*)&per1[2 * (size_t)(p & 0xFFFFu)];
            int dl = p >> 16;
            atomicAdd(&bins[2][dl], v.x);
            atomicAdd(&bins[3][dl], v.y);
        }
        __syncthreads();
        float* dst = part1 + ((size_t)(b * NCHK + ck) * 4) * RNGC;
#pragma unroll
        for (int c = 0; c < 4; ++c)
            for (int n = tid; n < RNGC; n += 1024)
                dst[c * RNGC + n] = bins[c][n];
    }
}

// ---- prep: relpre (bf16) + bias3 + W1T transpose (independent of scatter) ----
__global__ __launch_bounds__(256) void prep_kernel(
        const float* __restrict__ rel, const float* __restrict__ intent,
        const float* __restrict__ q, const float* __restrict__ W1,
        const float* __restrict__ b1,
        unsigned short* __restrict__ rel_bf, float* __restrict__ bias3,
        unsigned short* __restrict__ W1T,
        int relBlocks, int biasBlocks, int NREL) {
    int tid = threadIdx.x;
    int bid = blockIdx.x;
    if (bid < relBlocks) {
        int idx = bid * 256 + tid;
        int r = idx >> 7, j = idx & 127;
        if (r < NREL) {
            const float4* xr = (const float4*)(rel + (size_t)r * E);
            float acc = 0.f;
#pragma unroll
            for (int k4 = 0; k4 < 32; ++k4) {
                float4 x = xr[k4];
                int k = OFF_REL + k4 * 4;
                acc = fmaf(x.x, W1[(k + 0) * E + j], acc);
                acc = fmaf(x.y, W1[(k + 1) * E + j], acc);
                acc = fmaf(x.z, W1[(k + 2) * E + j], acc);
                acc = fmaf(x.w, W1[(k + 3) * E + j], acc);
            }
            rel_bf[idx] = f2bf(acc);
        }
    } else if (bid < relBlocks + biasBlocks) {
        // one wave per output (i,j): 384 outputs
        int widx = (bid - relBlocks) * 4 + (tid >> 6);
        int lane = tid & 63;
        if (widx < 384) {
            int i = widx >> 7, j = widx & 127;
            float sum = 0.f;
#pragma unroll
            for (int m = 0; m < 4; ++m) {
                int k = lane + 64 * m;
                float x = (k < 128) ? intent[i * E + k] : q[k - 128];
                sum = fmaf(x, W1[(size_t)k * E + j], sum);
            }
#pragma unroll
            for (int o = 32; o > 0; o >>= 1) sum += __shfl_xor(sum, o, 64);
            if (lane == 0) bias3[i * E + j] = sum + b1[j];
        }
    } else {
        // W1T[c][k] bf16: transposed head|tail W1 panel, K padded to KP
        int c = bid - relBlocks - biasBlocks;   // 0..255
        if (tid < KP) {
            int cc = (c < 128) ? c : c - 128;
            int base = (c < 128) ? OFF_HEAD : OFF_TAIL;
            float v = (tid < KTOT) ? W1[(size_t)(base + tid) * E + cc] : 0.f;
            W1T[(size_t)c * KP + tid] = f2bf(v);
        }
    }
}

// ---- head/tail precompute via MFMA; round-2 partials reduced inline ----
__global__ __launch_bounds__(256) void nodepre_mfma(
        const float* __restrict__ ent, const float* __restrict__ nontext,
        const float* __restrict__ topic,
        const float* __restrict__ pef1, const float* __restrict__ per1,
        const float* __restrict__ part2,
        const float* __restrict__ inv_fwd, const float* __restrict__ inv_rev,
        const unsigned short* __restrict__ W1T,
        unsigned short* __restrict__ head_bf, unsigned short* __restrict__ tail_bf,
        int N, int NTEXT) {
    __shared__ unsigned short As[64 * AST];
    int t = threadIdx.x;
    int lane = t & 63;
    int w = t >> 6;
    int l15 = lane & 15;
    int lg = lane >> 4;
    int n0 = blockIdx.x * 64;

    // stage A rows (k<128)
    {
        int row = t >> 2, ch = t & 3;
        int node = n0 + row;
        bool ok = node < N;
        const float* src = (node < NTEXT) ? (ent + (size_t)node * E) : nontext;
        unsigned* dst = (unsigned*)&As[row * AST + ch * 32];
#pragma unroll
        for (int qq = 0; qq < 8; ++qq) {
            float4 v = ok ? *(const float4*)(src + ch * 32 + qq * 4)
                          : make_float4(0.f, 0.f, 0.f, 0.f);
            dst[qq * 2 + 0] = bpack(v.x, v.y);
            dst[qq * 2 + 1] = bpack(v.z, v.w);
        }
    }
    // extras: topic->128,129  pef1->130,131  per1->134,135  zeros 138..159
    if (t < 64) {
        int node = n0 + t;
        bool ok = node < N;
        unsigned short* dst = &As[t * AST + 128];
        float ex[6];
        if (ok) {
            ex[0] = topic[2 * (size_t)node]; ex[1] = topic[2 * (size_t)node + 1];
            ex[2] = pef1[2 * (size_t)node];  ex[3] = pef1[2 * (size_t)node + 1];
            ex[4] = per1[2 * (size_t)node];  ex[5] = per1[2 * (size_t)node + 1];
        } else {
#pragma unroll
            for (int m = 0; m < 6; ++m) ex[m] = 0.f;
        }
        dst[0] = f2bf(ex[0]); dst[1] = f2bf(ex[1]);
        dst[2] = f2bf(ex[2]); dst[3] = f2bf(ex[3]);
        dst[6] = f2bf(ex[4]); dst[7] = f2bf(ex[5]);
#pragma unroll
        for (int m = 10; m < 32; ++m) dst[m] = 0;
    }
    // inline reduce of round-2 partials: pef2 -> 132,133 ; per2 -> 136,137
    {
        int nloc = t >> 2;
        int c = t & 3;
        int node = n0 + nloc;
        float val = 0.f;
        if (node < N) {
            int b = node >> 11, nl = node & 2047;
            const float* base = part2 + (size_t)b * NCHK * 4 * RNGC + nl;
            float s = 0.f;
#pragma unroll
            for (int ck = 0; ck < NCHK; ++ck)
                s += base[(ck * 4 + c) * RNGC];
            val = s * ((c < 2) ? inv_fwd[node] : inv_rev[node]);
        }
        int slot = (c < 2) ? (132 + c) : (134 + c);
        As[nloc * AST + (slot - 128) + 128] = f2bf(val);
    }
    __syncthreads();

    f32x4 zero = {0.f, 0.f, 0.f, 0.f};
    f32x4 acc[4][4];
#pragma unroll
    for (int rt = 0; rt < 4; ++rt)
#pragma unroll
        for (int ct = 0; ct < 4; ++ct) acc[rt][ct] = zero;

#pragma unroll
    for (int ks = 0; ks < 5; ++ks) {
        int kb = ks * 32 + lg * 8;
        short8 afrag[4];
#pragma unroll
        for (int rt = 0; rt < 4; ++rt)
            afrag[rt] = *(const short8*)&As[(rt * 16 + l15) * AST + kb];
#pragma unroll
        for (int ct = 0; ct < 4; ++ct) {
            int c = w * 64 + ct * 16 + l15;
            short8 b = *(const short8*)&W1T[(size_t)c * KP + kb];
#pragma unroll
            for (int rt = 0; rt < 4; ++rt)
                acc[rt][ct] = __builtin_amdgcn_mfma_f32_16x16x32_bf16(
                    afrag[rt], b, acc[rt][ct], 0, 0, 0);
        }
    }

#pragma unroll
    for (int rt = 0; rt < 4; ++rt) {
#pragma unroll
        for (int ct = 0; ct < 4; ++ct) {
            int c = w * 64 + ct * 16 + l15;
            unsigned short* base = (c < 128) ? head_bf : tail_bf;
            int cc = (c < 128) ? c : c - 128;
#pragma unroll
            for (int r = 0; r < 4; ++r) {
                int node = n0 + rt * 16 + lg * 4 + r;
                if (node < N) base[(size_t)node * E + cc] = f2bf(acc[rt][ct][r]);
            }
        }
    }
}

// ---- edge MLP: plain grid-stride, 16 lanes/edge, bf16 table gathers ----
__global__ __launch_bounds__(256) void edge_kernel(
        const int* __restrict__ h_id, const int* __restrict__ r_id, const int* __restrict__ t_id,
        const unsigned short* __restrict__ head_bf, const unsigned short* __restrict__ rel_bf,
        const unsigned short* __restrict__ tail_bf, const float* __restrict__ bias3,
        const float* __restrict__ W2, const float* __restrict__ b2,
        float* __restrict__ out, int T) {
    int lane = threadIdx.x & 63;
    int sub = lane >> 4;
    int sl = lane & 15;
    int wid = blockIdx.x * (blockDim.x >> 6) + (threadIdx.x >> 6);
    int nw = gridDim.x * (blockDim.x >> 6);
    int c0 = sl * 8;

    float4 bi0a = *(const float4*)&bias3[c0],         bi0b = *(const float4*)&bias3[c0 + 4];
    float4 bi1a = *(const float4*)&bias3[E + c0],     bi1b = *(const float4*)&bias3[E + c0 + 4];
    float4 bi2a = *(const float4*)&bias3[2 * E + c0], bi2b = *(const float4*)&bias3[2 * E + c0 + 4];
    float4 w2a = *(const float4*)&W2[c0], w2b = *(const float4*)&W2[c0 + 4];
    float b2s = b2[0];

    int ne4 = (T + 3) >> 2;
    for (int e4 = wid; e4 < ne4; e4 += nw) {
        int e = e4 * 4 + sub;
        float p0 = 0.f, p1 = 0.f, p2 = 0.f;
        if (e < T) {
            int h = h_id[e], r = r_id[e], tt = t_id[e];
            uint4 hu = *(const uint4*)(head_bf + (size_t)h * E + c0);
            uint4 ru = *(const uint4*)(rel_bf + (size_t)r * E + c0);
            uint4 tu = *(const uint4*)(tail_bf + (size_t)tt * E + c0);
            float sv[8];
            sv[0] = blo(hu.x) + blo(ru.x) + blo(tu.x);
            sv[1] = bhi(hu.x) + bhi(ru.x) + bhi(tu.x);
            sv[2] = blo(hu.y) + blo(ru.y) + blo(tu.y);
            sv[3] = bhi(hu.y) + bhi(ru.y) + bhi(tu.y);
            sv[4] = blo(hu.z) + blo(ru.z) + blo(tu.z);
            sv[5] = bhi(hu.z) + bhi(ru.z) + bhi(tu.z);
            sv[6] = blo(hu.w) + blo(ru.w) + blo(tu.w);
            sv[7] = bhi(hu.w) + bhi(ru.w) + bhi(tu.w);
            float bi0[8] = {bi0a.x, bi0a.y, bi0a.z, bi0a.w, bi0b.x, bi0b.y, bi0b.z, bi0b.w};
            float bi1[8] = {bi1a.x, bi1a.y, bi1a.z, bi1a.w, bi1b.x, bi1b.y, bi1b.z, bi1b.w};
            float bi2[8] = {bi2a.x, bi2a.y, bi2a.z, bi2a.w, bi2b.x, bi2b.y, bi2b.z, bi2b.w};
            float w2v[8] = {w2a.x, w2a.y, w2a.z, w2a.w, w2b.x, w2b.y, w2b.z, w2b.w};
#pragma unroll
            for (int j = 0; j < 8; ++j) {
                p0 = fmaf(fmaxf(sv[j] + bi0[j], 0.f), w2v[j], p0);
                p1 = fmaf(fmaxf(sv[j] + bi1[j], 0.f), w2v[j], p1);
                p2 = fmaf(fmaxf(sv[j] + bi2[j], 0.f), w2v[j], p2);
            }
        }
#pragma unroll
        for (int o = 1; o < 16; o <<= 1) {
            p0 += __shfl_xor(p0, o, 64);
            p1 += __shfl_xor(p1, o, 64);
            p2 += __shfl_xor(p2, o, 64);
        }
        if (e < T && sl < 3) {
            float v = (sl == 0) ? p0 : ((sl == 1) ? p1 : p2);
            out[(size_t)e * 3 + sl] = v + b2s;
        }
    }
}

extern "C" void kernel_launch(void* const* d_in, const int* in_sizes, int n_in,
                              void* d_out, int out_size, void* d_ws, size_t ws_size,
                              hipStream_t stream) {
    const int* h_id = (const int*)d_in[0];
    const int* r_id = (const int*)d_in[1];
    const int* t_id = (const int*)d_in[2];
    const float* q = (const float*)d_in[3];
    const float* ent = (const float*)d_in[4];
    const float* rel = (const float*)d_in[6];
    const float* topic = (const float*)d_in[7];
    const float* nontext = (const float*)d_in[8];
    const float* intent = (const float*)d_in[9];
    const float* W1 = (const float*)d_in[10];
    const float* b1 = (const float*)d_in[11];
    const float* W2 = (const float*)d_in[12];
    const float* b2 = (const float*)d_in[13];

    int T = in_sizes[0];
    int NTEXT = in_sizes[4] / E;
    int N = in_sizes[7] / 2;
    int NREL = in_sizes[6] / E;

    int RC = (N + RNGC - 1) / RNGC;                           // 25

    unsigned* curs = (unsigned*)d_ws;                         // 64 u32
    unsigned* pairs_f = curs + 64;                            // 32*CAP
    unsigned* pairs_r = pairs_f + (size_t)32 * CAP;           // 32*CAP
    float* part1 = (float*)(pairs_r + (size_t)32 * CAP);      // RC*NCHK*6*RNGC
    float* inv_fwd = part1 + (size_t)RC * NCHK * 6 * RNGC;    // N
    float* inv_rev = inv_fwd + N;                             // N
    float* pef1 = inv_rev + N;                                // 2N
    float* per1 = pef1 + 2 * (size_t)N;                       // 2N
    float* bias3 = per1 + 2 * (size_t)N;                      // 384
    unsigned short* W1T = (unsigned short*)(bias3 + 3 * E);   // 256*KP
    unsigned short* rel_bf = W1T + 256 * KP;                  // NREL*E
    unsigned short* head_bf = rel_bf + (size_t)NREL * E;      // N*E
    unsigned short* tail_bf = head_bf + (size_t)N * E;        // N*E

    const int tb = 256;
    int relBlocks = (NREL * E + tb - 1) / tb;                 // 250
    int biasBlocks = 96;                                      // 384 waves

    // prep is independent of the scatter pipeline -> launch first
    prep_kernel<<<relBlocks + biasBlocks + 256, tb, 0, stream>>>(
        rel, intent, q, W1, b1, rel_bf, bias3, W1T, relBlocks, biasBlocks, NREL);

    {
        int Tl = T, Nl = N;
        void* args[] = {(void*)&h_id, (void*)&t_id, (void*)&topic,
                        (void*)&curs, (void*)&pairs_f, (void*)&pairs_r,
                        (void*)&part1, (void*)&pef1, (void*)&per1,
                        (void*)&inv_fwd, (void*)&inv_rev,
                        (void*)&Tl, (void*)&Nl};
        hipLaunchCooperativeKernel((void*)scatter_coop, dim3(RC * NCHK), dim3(1024),
                                   args, 0, stream);
    }

    nodepre_mfma<<<(N + 63) / 64, tb, 0, stream>>>(ent, nontext, topic, pef1, per1,
                                                   part1, inv_fwd, inv_rev, W1T,
                                                   head_bf, tail_bf, N, NTEXT);
    edge_kernel<<<2048, tb, 0, stream>>>(h_id, r_id, t_id, head_bf, rel_bf, tail_bf,
                                         bias3, W2, b2, (float*)d_out, T);
}

// Round 15
// 108.608 us; speedup vs baseline: 1.8452x; 1.8452x over previous
//
#include <hip/hip_runtime.h>

#define E 128
#define OFF_Q 128
#define OFF_HEAD 256
#define OFF_REL 394
#define OFF_TAIL 522
#define KTOT 138      // 128 + 2 + 2*4
#define KP 160
#define AST 168       // LDS A row stride in bf16 for nodepre
#define RNGC 2048     // nodes per range bucket
#define NCHK 8        // chunks per range (scatter parallelism)
#define CAP 16384     // slots per bucket (expected ~12K, fixed input, big margin)

typedef __attribute__((ext_vector_type(8))) short short8;
typedef __attribute__((ext_vector_type(4))) float f32x4;

// ---- bf16 helpers (RNE, finite values only) ----
__device__ __forceinline__ unsigned short f2bf(float f) {
    unsigned u = __float_as_uint(f);
    return (unsigned short)((u + 0x7fffu + ((u >> 16) & 1u)) >> 16);
}
__device__ __forceinline__ unsigned bpack(float lo, float hi) {
    return (unsigned)f2bf(lo) | ((unsigned)f2bf(hi) << 16);
}
__device__ __forceinline__ float blo(unsigned u) { return __uint_as_float(u << 16); }
__device__ __forceinline__ float bhi(unsigned u) { return __uint_as_float(u & 0xffff0000u); }

// ---- fused: bucket pass + relpre + bias + W1T transpose ----
// pairs_f[bucket(t)]: u32 = h | (tlocal<<16);  pairs_r[bucket(h)]: t | (hlocal<<16)
__global__ __launch_bounds__(256) void bucket_prep_kernel(
        const int* __restrict__ h_id, const int* __restrict__ t_id,
        const float* __restrict__ rel, const float* __restrict__ intent,
        const float* __restrict__ q, const float* __restrict__ W1,
        const float* __restrict__ b1,
        unsigned* __restrict__ curs, unsigned* __restrict__ pairs_f,
        unsigned* __restrict__ pairs_r,
        unsigned short* __restrict__ rel_bf, float* __restrict__ bias3,
        unsigned short* __restrict__ W1T,
        int T, int bucketBlocks, int relBlocks, int biasBlocks, int NREL) {
    int tid = threadIdx.x;
    int bid = blockIdx.x;

    if (bid < bucketBlocks) {
        __shared__ unsigned hf[32], hr[32], basef[32], baser[32];
        if (tid < 32) { hf[tid] = 0; hr[tid] = 0; }
        __syncthreads();
        int e0 = (bid * 256 + tid) * 4;
        int hh[4], tt[4];
        int cnt = 0;
        if (e0 < T) {
            if (e0 + 3 < T) {
                int4 h4 = *(const int4*)&h_id[e0];
                int4 t4 = *(const int4*)&t_id[e0];
                hh[0] = h4.x; hh[1] = h4.y; hh[2] = h4.z; hh[3] = h4.w;
                tt[0] = t4.x; tt[1] = t4.y; tt[2] = t4.z; tt[3] = t4.w;
                cnt = 4;
            } else {
                for (int j = 0; e0 + j < T && j < 4; ++j) {
                    hh[j] = h_id[e0 + j];
                    tt[j] = t_id[e0 + j];
                    ++cnt;
                }
            }
        }
        unsigned bf[4], br[4];
        for (int j = 0; j < cnt; ++j) {
            bf[j] = (unsigned)tt[j] >> 11;
            br[j] = (unsigned)hh[j] >> 11;
            atomicAdd(&hf[bf[j]], 1u);
            atomicAdd(&hr[br[j]], 1u);
        }
        __syncthreads();
        if (tid < 32) {
            basef[tid] = hf[tid] ? atomicAdd(&curs[tid], hf[tid]) : 0u;
            baser[tid] = hr[tid] ? atomicAdd(&curs[32 + tid], hr[tid]) : 0u;
        }
        __syncthreads();
        if (tid < 32) { hf[tid] = 0; hr[tid] = 0; }
        __syncthreads();
        for (int j = 0; j < cnt; ++j) {
            unsigned sf = basef[bf[j]] + atomicAdd(&hf[bf[j]], 1u);
            if (sf < CAP) pairs_f[bf[j] * CAP + sf] =
                (unsigned)hh[j] | (((unsigned)tt[j] & 2047u) << 16);
            unsigned sr = baser[br[j]] + atomicAdd(&hr[br[j]], 1u);
            if (sr < CAP) pairs_r[br[j] * CAP + sr] =
                (unsigned)tt[j] | (((unsigned)hh[j] & 2047u) << 16);
        }
    } else if (bid < bucketBlocks + relBlocks) {
        int idx = (bid - bucketBlocks) * 256 + tid;
        int r = idx >> 7, j = idx & 127;
        if (r < NREL) {
            const float4* xr = (const float4*)(rel + (size_t)r * E);
            float acc = 0.f;
#pragma unroll
            for (int k4 = 0; k4 < 32; ++k4) {
                float4 x = xr[k4];
                int k = OFF_REL + k4 * 4;
                acc = fmaf(x.x, W1[(k + 0) * E + j], acc);
                acc = fmaf(x.y, W1[(k + 1) * E + j], acc);
                acc = fmaf(x.z, W1[(k + 2) * E + j], acc);
                acc = fmaf(x.w, W1[(k + 3) * E + j], acc);
            }
            rel_bf[idx] = f2bf(acc);
        }
    } else if (bid < bucketBlocks + relBlocks + biasBlocks) {
        // one wave per output (i,j): 384 outputs
        int widx = (bid - bucketBlocks - relBlocks) * 4 + (tid >> 6);
        int lane = tid & 63;
        if (widx < 384) {
            int i = widx >> 7, j = widx & 127;
            float sum = 0.f;
#pragma unroll
            for (int m = 0; m < 4; ++m) {
                int k = lane + 64 * m;
                float x = (k < 128) ? intent[i * E + k] : q[k - 128];
                sum = fmaf(x, W1[(size_t)k * E + j], sum);
            }
#pragma unroll
            for (int o = 32; o > 0; o >>= 1) sum += __shfl_xor(sum, o, 64);
            if (lane == 0) bias3[i * E + j] = sum + b1[j];
        }
    } else {
        // W1T[c][k] bf16: transposed head|tail W1 panel, K padded to KP
        int c = bid - bucketBlocks - relBlocks - biasBlocks;   // 0..255
        if (tid < KP) {
            int cc = (c < 128) ? c : c - 128;
            int base = (c < 128) ? OFF_HEAD : OFF_TAIL;
            float v = (tid < KTOT) ? W1[(size_t)(base + tid) * E + cc] : 0.f;
            W1T[(size_t)c * KP + tid] = f2bf(v);
        }
    }
}

// ---- round-1 conv: grid (range, chunk), LDS bins, non-atomic partials ----
__global__ __launch_bounds__(1024) void scat1_kernel(
        const unsigned* __restrict__ pairs_f, const unsigned* __restrict__ pairs_r,
        const unsigned* __restrict__ curs, const float* __restrict__ topic,
        float* __restrict__ part1) {
    __shared__ float bins[6][RNGC];
    int b = blockIdx.x;
    int ck = blockIdx.y;
    int tid = threadIdx.x;
    for (int i = tid; i < 6 * RNGC; i += 1024) ((float*)bins)[i] = 0.f;
    __syncthreads();
    unsigned cf = min(curs[b], (unsigned)CAP);
    unsigned cr = min(curs[32 + b], (unsigned)CAP);
    const unsigned* pf = pairs_f + (size_t)b * CAP;
    const unsigned* pr = pairs_r + (size_t)b * CAP;
    unsigned lf = (cf + NCHK - 1) / NCHK;
    unsigned lr = (cr + NCHK - 1) / NCHK;
    unsigned f0 = ck * lf, f1e = min(cf, f0 + lf);
    unsigned r0 = ck * lr, r1e = min(cr, r0 + lr);
    for (unsigned i = f0 + tid; i < f1e; i += 1024) {
        unsigned p = pf[i];
        float2 v = *(const float2*)&topic[2 * (size_t)(p & 0xFFFFu)];
        int dl = p >> 16;
        atomicAdd(&bins[0][dl], v.x);
        atomicAdd(&bins[1][dl], v.y);
        atomicAdd(&bins[2][dl], 1.0f);
    }
    for (unsigned i = r0 + tid; i < r1e; i += 1024) {
        unsigned p = pr[i];
        float2 v = *(const float2*)&topic[2 * (size_t)(p & 0xFFFFu)];
        int dl = p >> 16;
        atomicAdd(&bins[3][dl], v.x);
        atomicAdd(&bins[4][dl], v.y);
        atomicAdd(&bins[5][dl], 1.0f);
    }
    __syncthreads();
    float* dst = part1 + ((size_t)(b * NCHK + ck) * 6) * RNGC;
#pragma unroll
    for (int c = 0; c < 6; ++c)
        for (int n = tid; n < RNGC; n += 1024)
            dst[c * RNGC + n] = bins[c][n];
}

// ---- reduce round-1 partials -> scaled pef1/per1 + inv arrays ----
__global__ __launch_bounds__(256) void reduce1_kernel(
        const float* __restrict__ part1,
        float* __restrict__ pef1, float* __restrict__ per1,
        float* __restrict__ inv_fwd, float* __restrict__ inv_rev, int N) {
    int n = blockIdx.x * 256 + threadIdx.x;
    if (n >= N) return;
    int b = n >> 11, nl = n & 2047;
    float s[6] = {0.f, 0.f, 0.f, 0.f, 0.f, 0.f};
    const float* base = part1 + (size_t)b * NCHK * 6 * RNGC + nl;
#pragma unroll
    for (int ck = 0; ck < NCHK; ++ck)
#pragma unroll
        for (int c = 0; c < 6; ++c)
            s[c] += base[(ck * 6 + c) * RNGC];
    float invf = 1.0f / fmaxf(s[2], 1.0f);
    float invr = 1.0f / fmaxf(s[5], 1.0f);
    pef1[2 * n] = s[0] * invf;
    pef1[2 * n + 1] = s[1] * invf;
    per1[2 * n] = s[3] * invr;
    per1[2 * n + 1] = s[4] * invr;
    inv_fwd[n] = invf;
    inv_rev[n] = invr;
}

// ---- round-2 conv: gathers scaled pef1/per1, partials part2 (aliases part1) ----
__global__ __launch_bounds__(1024) void scat2_kernel(
        const unsigned* __restrict__ pairs_f, const unsigned* __restrict__ pairs_r,
        const unsigned* __restrict__ curs,
        const float* __restrict__ pef1, const float* __restrict__ per1,
        float* __restrict__ part2) {
    __shared__ float bins[4][RNGC];
    int b = blockIdx.x;
    int ck = blockIdx.y;
    int tid = threadIdx.x;
    for (int i = tid; i < 4 * RNGC; i += 1024) ((float*)bins)[i] = 0.f;
    __syncthreads();
    unsigned cf = min(curs[b], (unsigned)CAP);
    unsigned cr = min(curs[32 + b], (unsigned)CAP);
    const unsigned* pf = pairs_f + (size_t)b * CAP;
    const unsigned* pr = pairs_r + (size_t)b * CAP;
    unsigned lf = (cf + NCHK - 1) / NCHK;
    unsigned lr = (cr + NCHK - 1) / NCHK;
    unsigned f0 = ck * lf, f1e = min(cf, f0 + lf);
    unsigned r0 = ck * lr, r1e = min(cr, r0 + lr);
    for (unsigned i = f0 + tid; i < f1e; i += 1024) {
        unsigned p = pf[i];
        float2 v = *(const float2*)&pef1[2 * (size_t)(p & 0xFFFFu)];
        int dl = p >> 16;
        atomicAdd(&bins[0][dl], v.x);
        atomicAdd(&bins[1][dl], v.y);
    }
    for (unsigned i = r0 + tid; i < r1e; i += 1024) {
        unsigned p = pr[i];
        float2 v = *(const float2*)&per1[2 * (size_t)(p & 0xFFFFu)];
        int dl = p >> 16;
        atomicAdd(&bins[2][dl], v.x);
        atomicAdd(&bins[3][dl], v.y);
    }
    __syncthreads();
    float* dst = part2 + ((size_t)(b * NCHK + ck) * 4) * RNGC;
#pragma unroll
    for (int c = 0; c < 4; ++c)
        for (int n = tid; n < RNGC; n += 1024)
            dst[c * RNGC + n] = bins[c][n];
}

// ---- head/tail precompute via MFMA; round-2 partials reduced inline ----
__global__ __launch_bounds__(256) void nodepre_mfma(
        const float* __restrict__ ent, const float* __restrict__ nontext,
        const float* __restrict__ topic,
        const float* __restrict__ pef1, const float* __restrict__ per1,
        const float* __restrict__ part2,
        const float* __restrict__ inv_fwd, const float* __restrict__ inv_rev,
        const unsigned short* __restrict__ W1T,
        unsigned short* __restrict__ head_bf, unsigned short* __restrict__ tail_bf,
        int N, int NTEXT) {
    __shared__ unsigned short As[64 * AST];
    int t = threadIdx.x;
    int lane = t & 63;
    int w = t >> 6;
    int l15 = lane & 15;
    int lg = lane >> 4;
    int n0 = blockIdx.x * 64;

    // stage A rows (k<128)
    {
        int row = t >> 2, ch = t & 3;
        int node = n0 + row;
        bool ok = node < N;
        const float* src = (node < NTEXT) ? (ent + (size_t)node * E) : nontext;
        unsigned* dst = (unsigned*)&As[row * AST + ch * 32];
#pragma unroll
        for (int qq = 0; qq < 8; ++qq) {
            float4 v = ok ? *(const float4*)(src + ch * 32 + qq * 4)
                          : make_float4(0.f, 0.f, 0.f, 0.f);
            dst[qq * 2 + 0] = bpack(v.x, v.y);
            dst[qq * 2 + 1] = bpack(v.z, v.w);
        }
    }
    // extras: topic->128,129  pef1->130,131  per1->134,135  zeros 138..159
    if (t < 64) {
        int node = n0 + t;
        bool ok = node < N;
        unsigned short* dst = &As[t * AST + 128];
        float ex[6];
        if (ok) {
            ex[0] = topic[2 * (size_t)node]; ex[1] = topic[2 * (size_t)node + 1];
            ex[2] = pef1[2 * (size_t)node];  ex[3] = pef1[2 * (size_t)node + 1];
            ex[4] = per1[2 * (size_t)node];  ex[5] = per1[2 * (size_t)node + 1];
        } else {
#pragma unroll
            for (int m = 0; m < 6; ++m) ex[m] = 0.f;
        }
        dst[0] = f2bf(ex[0]); dst[1] = f2bf(ex[1]);
        dst[2] = f2bf(ex[2]); dst[3] = f2bf(ex[3]);
        dst[6] = f2bf(ex[4]); dst[7] = f2bf(ex[5]);
#pragma unroll
        for (int m = 10; m < 32; ++m) dst[m] = 0;
    }
    // inline reduce of round-2 partials: pef2 -> 132,133 ; per2 -> 136,137
    {
        int nloc = t >> 2;
        int c = t & 3;
        int node = n0 + nloc;
        float val = 0.f;
        if (node < N) {
            int b = node >> 11, nl = node & 2047;
            const float* base = part2 + (size_t)b * NCHK * 4 * RNGC + nl;
            float s = 0.f;
#pragma unroll
            for (int ck = 0; ck < NCHK; ++ck)
                s += base[(ck * 4 + c) * RNGC];
            val = s * ((c < 2) ? inv_fwd[node] : inv_rev[node]);
        }
        int slot = (c < 2) ? (132 + c) : (134 + c);
        As[nloc * AST + (slot - 128) + 128] = f2bf(val);
    }
    __syncthreads();

    f32x4 zero = {0.f, 0.f, 0.f, 0.f};
    f32x4 acc[4][4];
#pragma unroll
    for (int rt = 0; rt < 4; ++rt)
#pragma unroll
        for (int ct = 0; ct < 4; ++ct) acc[rt][ct] = zero;

#pragma unroll
    for (int ks = 0; ks < 5; ++ks) {
        int kb = ks * 32 + lg * 8;
        short8 afrag[4];
#pragma unroll
        for (int rt = 0; rt < 4; ++rt)
            afrag[rt] = *(const short8*)&As[(rt * 16 + l15) * AST + kb];
#pragma unroll
        for (int ct = 0; ct < 4; ++ct) {
            int c = w * 64 + ct * 16 + l15;
            short8 b = *(const short8*)&W1T[(size_t)c * KP + kb];
#pragma unroll
            for (int rt = 0; rt < 4; ++rt)
                acc[rt][ct] = __builtin_amdgcn_mfma_f32_16x16x32_bf16(
                    afrag[rt], b, acc[rt][ct], 0, 0, 0);
        }
    }

#pragma unroll
    for (int rt = 0; rt < 4; ++rt) {
#pragma unroll
        for (int ct = 0; ct < 4; ++ct) {
            int c = w * 64 + ct * 16 + l15;
            unsigned short* base = (c < 128) ? head_bf : tail_bf;
            int cc = (c < 128) ? c : c - 128;
#pragma unroll
            for (int r = 0; r < 4; ++r) {
                int node = n0 + rt * 16 + lg * 4 + r;
                if (node < N) base[(size_t)node * E + cc] = f2bf(acc[rt][ct][r]);
            }
        }
    }
}

// ---- edge MLP: plain grid-stride, 16 lanes/edge, bf16 table gathers ----
__global__ __launch_bounds__(256) void edge_kernel(
        const int* __restrict__ h_id, const int* __restrict__ r_id, const int* __restrict__ t_id,
        const unsigned short* __restrict__ head_bf, const unsigned short* __restrict__ rel_bf,
        const unsigned short* __restrict__ tail_bf, const float* __restrict__ bias3,
        const float* __restrict__ W2, const float* __restrict__ b2,
        float* __restrict__ out, int T) {
    int lane = threadIdx.x & 63;
    int sub = lane >> 4;
    int sl = lane & 15;
    int wid = blockIdx.x * (blockDim.x >> 6) + (threadIdx.x >> 6);
    int nw = gridDim.x * (blockDim.x >> 6);
    int c0 = sl * 8;

    float4 bi0a = *(const float4*)&bias3[c0],         bi0b = *(const float4*)&bias3[c0 + 4];
    float4 bi1a = *(const float4*)&bias3[E + c0],     bi1b = *(const float4*)&bias3[E + c0 + 4];
    float4 bi2a = *(const float4*)&bias3[2 * E + c0], bi2b = *(const float4*)&bias3[2 * E + c0 + 4];
    float4 w2a = *(const float4*)&W2[c0], w2b = *(const float4*)&W2[c0 + 4];
    float b2s = b2[0];

    int ne4 = (T + 3) >> 2;
    for (int e4 = wid; e4 < ne4; e4 += nw) {
        int e = e4 * 4 + sub;
        float p0 = 0.f, p1 = 0.f, p2 = 0.f;
        if (e < T) {
            int h = h_id[e], r = r_id[e], tt = t_id[e];
            uint4 hu = *(const uint4*)(head_bf + (size_t)h * E + c0);
            uint4 ru = *(const uint4*)(rel_bf + (size_t)r * E + c0);
            uint4 tu = *(const uint4*)(tail_bf + (size_t)tt * E + c0);
            float sv[8];
            sv[0] = blo(hu.x) + blo(ru.x) + blo(tu.x);
            sv[1] = bhi(hu.x) + bhi(ru.x) + bhi(tu.x);
            sv[2] = blo(hu.y) + blo(ru.y) + blo(tu.y);
            sv[3] = bhi(hu.y) + bhi(ru.y) + bhi(tu.y);
            sv[4] = blo(hu.z) + blo(ru.z) + blo(tu.z);
            sv[5] = bhi(hu.z) + bhi(ru.z) + bhi(tu.z);
            sv[6] = blo(hu.w) + blo(ru.w) + blo(tu.w);
            sv[7] = bhi(hu.w) + bhi(ru.w) + bhi(tu.w);
            float bi0[8] = {bi0a.x, bi0a.y, bi0a.z, bi0a.w, bi0b.x, bi0b.y, bi0b.z, bi0b.w};
            float bi1[8] = {bi1a.x, bi1a.y, bi1a.z, bi1a.w, bi1b.x, bi1b.y, bi1b.z, bi1b.w};
            float bi2[8] = {bi2a.x, bi2a.y, bi2a.z, bi2a.w, bi2b.x, bi2b.y, bi2b.z, bi2b.w};
            float w2v[8] = {w2a.x, w2a.y, w2a.z, w2a.w, w2b.x, w2b.y, w2b.z, w2b.w};
#pragma unroll
            for (int j = 0; j < 8; ++j) {
                p0 = fmaf(fmaxf(sv[j] + bi0[j], 0.f), w2v[j], p0);
                p1 = fmaf(fmaxf(sv[j] + bi1[j], 0.f), w2v[j], p1);
                p2 = fmaf(fmaxf(sv[j] + bi2[j], 0.f), w2v[j], p2);
            }
        }
#pragma unroll
        for (int o = 1; o < 16; o <<= 1) {
            p0 += __shfl_xor(p0, o, 64);
            p1 += __shfl_xor(p1, o, 64);
            p2 += __shfl_xor(p2, o, 64);
        }
        if (e < T && sl < 3) {
            float v = (sl == 0) ? p0 : ((sl == 1) ? p1 : p2);
            out[(size_t)e * 3 + sl] = v + b2s;
        }
    }
}

extern "C" void kernel_launch(void* const* d_in, const int* in_sizes, int n_in,
                              void* d_out, int out_size, void* d_ws, size_t ws_size,
                              hipStream_t stream) {
    const int* h_id = (const int*)d_in[0];
    const int* r_id = (const int*)d_in[1];
    const int* t_id = (const int*)d_in[2];
    const float* q = (const float*)d_in[3];
    const float* ent = (const float*)d_in[4];
    const float* rel = (const float*)d_in[6];
    const float* topic = (const float*)d_in[7];
    const float* nontext = (const float*)d_in[8];
    const float* intent = (const float*)d_in[9];
    const float* W1 = (const float*)d_in[10];
    const float* b1 = (const float*)d_in[11];
    const float* W2 = (const float*)d_in[12];
    const float* b2 = (const float*)d_in[13];

    int T = in_sizes[0];
    int NTEXT = in_sizes[4] / E;
    int N = in_sizes[7] / 2;
    int NREL = in_sizes[6] / E;

    int RC = (N + RNGC - 1) / RNGC;                           // 25

    unsigned* curs = (unsigned*)d_ws;                         // 64 u32
    unsigned* pairs_f = curs + 64;                            // 32*CAP
    unsigned* pairs_r = pairs_f + (size_t)32 * CAP;           // 32*CAP
    float* part1 = (float*)(pairs_r + (size_t)32 * CAP);      // RC*NCHK*6*RNGC
    float* inv_fwd = part1 + (size_t)RC * NCHK * 6 * RNGC;    // N
    float* inv_rev = inv_fwd + N;                             // N
    float* pef1 = inv_rev + N;                                // 2N
    float* per1 = pef1 + 2 * (size_t)N;                       // 2N
    float* bias3 = per1 + 2 * (size_t)N;                      // 384
    unsigned short* W1T = (unsigned short*)(bias3 + 3 * E);   // 256*KP
    unsigned short* rel_bf = W1T + 256 * KP;                  // NREL*E
    unsigned short* head_bf = rel_bf + (size_t)NREL * E;      // N*E
    unsigned short* tail_bf = head_bf + (size_t)N * E;        // N*E

    const int tb = 256;
    int bucketBlocks = (T + tb * 4 - 1) / (tb * 4);           // 293
    int relBlocks = (NREL * E + tb - 1) / tb;                 // 250
    int biasBlocks = 96;                                      // 384 waves

    hipMemsetAsync(curs, 0, 64 * sizeof(unsigned), stream);

    bucket_prep_kernel<<<bucketBlocks + relBlocks + biasBlocks + 256, tb, 0, stream>>>(
        h_id, t_id, rel, intent, q, W1, b1, curs, pairs_f, pairs_r,
        rel_bf, bias3, W1T, T, bucketBlocks, relBlocks, biasBlocks, NREL);
    scat1_kernel<<<dim3(RC, NCHK), 1024, 0, stream>>>(pairs_f, pairs_r, curs, topic, part1);
    reduce1_kernel<<<(N + tb - 1) / tb, tb, 0, stream>>>(part1, pef1, per1, inv_fwd, inv_rev, N);
    scat2_kernel<<<dim3(RC, NCHK), 1024, 0, stream>>>(pairs_f, pairs_r, curs, pef1, per1, part1);
    nodepre_mfma<<<(N + 63) / 64, tb, 0, stream>>>(ent, nontext, topic, pef1, per1,
                                                   part1, inv_fwd, inv_rev, W1T,
                                                   head_bf, tail_bf, N, NTEXT);
    edge_kernel<<<2048, tb, 0, stream>>>(h_id, r_id, t_id, head_bf, rel_bf, tail_bf,
                                         bias3, W2, b2, (float*)d_out, T);
}